// Round 2
// baseline (513.814 us; speedup 1.0000x reference)
//
#include <hip/hip_runtime.h>

// ---------------- problem constants ----------------
#define NCLS   100000
#define CPAD   100096          // 782 * 128, padded class count
#define EMB    512
#define BATCH  512
#define NBN    782             // N tiles of 128
#define NJ     1564            // NBN * 2 (per-wave-column lse partials)

#define S_F     64.0f
#define COS_M_F 0.8775825619f   // cos(0.5)
#define SIN_M_F 0.4794255386f   // sin(0.5)
#define TH_F   (-0.8775825619f) // cos(pi-0.5)
#define MM_F    0.2397127693f   // sin(pi-0.5)*0.5

// ws layout (bytes)
#define WS_ABF   0ull                      // 512*512 bf16          = 524288
#define WS_INV   524288ull                 // CPAD f32              = 400384
#define WS_PMAX  924672ull                 // 512*NJ f32            = 3203072
#define WS_PSUM  4127744ull                // 512*NJ f32            = 3203072
#define WS_NLL   7330816ull                // 512 f32               = 2048
#define WS_EXACT 7332864ull                // 512 f32               = 2048
#define WS_WBF   7334912ull                // CPAD*512 bf16         = 102498304
#define WS_NEED_FAST 109833216ull
typedef unsigned short ushort_t;

typedef __attribute__((ext_vector_type(8))) short bf16x8;
typedef __attribute__((ext_vector_type(4))) float floatx4;

__device__ __forceinline__ unsigned short f2bf(float f) {
    union { float f; unsigned int u; } c; c.f = f;
    unsigned int r = c.u + 0x7FFFu + ((c.u >> 16) & 1u);   // RNE
    return (unsigned short)(r >> 16);
}

__device__ __forceinline__ void load_lds16(const void* g, void* l) {
    __builtin_amdgcn_global_load_lds(
        (const __attribute__((address_space(1))) void*)g,
        (__attribute__((address_space(3))) void*)l, 16, 0, 0);
}

// ---------------- K0: input fp32 -> bf16 ----------------
__global__ __launch_bounds__(256) void cvt_input_kernel(
    const float* __restrict__ in, ushort_t* __restrict__ Abf) {
    int gid = blockIdx.x * 256 + threadIdx.x;          // 65536 threads, 4 elems each
    float4 f = ((const float4*)in)[gid];
    uint2 u;
    u.x = (unsigned)f2bf(f.x) | ((unsigned)f2bf(f.y) << 16);
    u.y = (unsigned)f2bf(f.z) | ((unsigned)f2bf(f.w) << 16);
    ((uint2*)Abf)[gid] = u;
}

// ---------------- K1: row norms (+ optional normalized bf16 weight) ----------------
template <bool WRITE_WBF>
__global__ __launch_bounds__(256) void norms_kernel(
    const float* __restrict__ W, ushort_t* __restrict__ Wbf,
    float* __restrict__ inv_norm) {
    int t = threadIdx.x;
    int lane = t & 63;
    int r = blockIdx.x * 4 + (t >> 6);                 // one wave per row, r < CPAD
    float4 f0 = make_float4(0.f, 0.f, 0.f, 0.f);
    float4 f1 = make_float4(0.f, 0.f, 0.f, 0.f);
    float ssq = 0.f;
    if (r < NCLS) {
        const float4* rp = (const float4*)(W + (size_t)r * EMB);
        f0 = rp[lane * 2];
        f1 = rp[lane * 2 + 1];
        ssq = f0.x*f0.x + f0.y*f0.y + f0.z*f0.z + f0.w*f0.w
            + f1.x*f1.x + f1.y*f1.y + f1.z*f1.z + f1.w*f1.w;
    }
    #pragma unroll
    for (int msk = 1; msk < 64; msk <<= 1) ssq += __shfl_xor(ssq, msk);
    float inv = 0.f;
    if (r < NCLS) inv = 1.0f / fmaxf(sqrtf(ssq), 1e-12f);
    if (lane == 0 && r < CPAD) inv_norm[r] = inv;
    if (WRITE_WBF) {
        uint4 u;
        u.x = (unsigned)f2bf(f0.x*inv) | ((unsigned)f2bf(f0.y*inv) << 16);
        u.y = (unsigned)f2bf(f0.z*inv) | ((unsigned)f2bf(f0.w*inv) << 16);
        u.z = (unsigned)f2bf(f1.x*inv) | ((unsigned)f2bf(f1.y*inv) << 16);
        u.w = (unsigned)f2bf(f1.z*inv) | ((unsigned)f2bf(f1.w*inv) << 16);
        ((uint4*)(Wbf + (size_t)r * EMB))[lane] = u;
    }
}

// ---------------- K1b: exact fp32 label-column cosine + phi ----------------
__global__ __launch_bounds__(256) void exact_label_kernel(
    const float* __restrict__ input, const float* __restrict__ W,
    const float* __restrict__ inv_norm, const int* __restrict__ label,
    float* __restrict__ exact_val) {
    const int t = threadIdx.x;
    const int lane = t & 63;
    const int row = blockIdx.x * 4 + (t >> 6);         // 128 blocks x 4 waves
    const int lab = label[row];
    const float4* ip = (const float4*)(input + (size_t)row * EMB);
    const float4* wp = (const float4*)(W + (size_t)lab * EMB);
    float4 a0 = ip[lane], a1 = ip[64 + lane];
    float4 b0 = wp[lane], b1 = wp[64 + lane];
    float dot = a0.x*b0.x + a0.y*b0.y + a0.z*b0.z + a0.w*b0.w
              + a1.x*b1.x + a1.y*b1.y + a1.z*b1.z + a1.w*b1.w;
    #pragma unroll
    for (int msk = 1; msk < 64; msk <<= 1) dot += __shfl_xor(dot, msk);
    if (lane == 0) {
        float c = dot * inv_norm[lab];
        float sine = sqrtf(fmaxf(1.0f - c * c, 0.0f));
        float phi = c * COS_M_F - sine * SIN_M_F;
        phi = (c > TH_F) ? phi : (c - MM_F);
        exact_val[row] = S_F * phi;
    }
}

// ---------------- K2: GEMM + arcface epilogue + lse partials ----------------
// BSRC==0: B from normalized bf16 weight in ws (global_load_lds)
// BSRC==1: B from fp32 weight, reg-staged + converted; inv_norm applied in epilogue
template <int BSRC>
__global__ __launch_bounds__(256) void gemm_kernel(
    const ushort_t* __restrict__ Abf,   // [512][512] bf16
    const float*    __restrict__ Wfp,   // [NCLS][512] fp32
    const ushort_t* __restrict__ Wbf,   // [CPAD][512] bf16 normalized
    const float*    __restrict__ inv_norm,
    const int*      __restrict__ label,
    const float*    __restrict__ exact_val,
    float*          __restrict__ out,   // [512][NCLS]
    float* __restrict__ pmax, float* __restrict__ psum) {
    __shared__ ushort_t As[128][64];
    __shared__ ushort_t Bs[128][64];

    const int t = threadIdx.x;
    const int lane = t & 63, wid = t >> 6;
    const int wr = wid >> 1, wc = wid & 1;       // 2x2 waves, each 64x64 out
    const int bid = blockIdx.x;
    const int mblk = bid & 3, nblk = bid >> 2;
    const int m0 = mblk * 128;
    const int c0 = nblk * 128;

    floatx4 acc[4][4] = {};

    for (int k0 = 0; k0 < EMB; k0 += 64) {
        __syncthreads();
        // ---- stage A (bf16, global_load_lds x4) ----
        #pragma unroll
        for (int r = 0; r < 4; ++r) {
            int i = r * 256 + t;                       // 8-elem chunk id
            int row = i >> 3, col = (i & 7) << 3;
            const ushort_t* gp = Abf + (size_t)(m0 + row) * EMB + k0 + col;
            load_lds16(gp, (char*)(&As[0][0]) + (size_t)(r * 256 + wid * 64) * 16);
        }
        // ---- stage B ----
        if constexpr (BSRC == 0) {
            #pragma unroll
            for (int r = 0; r < 4; ++r) {
                int i = r * 256 + t;
                int row = i >> 3, col = (i & 7) << 3;
                const ushort_t* gp = Wbf + (size_t)(c0 + row) * EMB + k0 + col;
                load_lds16(gp, (char*)(&Bs[0][0]) + (size_t)(r * 256 + wid * 64) * 16);
            }
        } else {
            #pragma unroll
            for (int r = 0; r < 4; ++r) {
                int i = r * 256 + t;
                int row = i >> 3, ck = (i & 7) << 3;
                int c = c0 + row;
                bf16x8 v = {0, 0, 0, 0, 0, 0, 0, 0};
                if (c < NCLS) {
                    const float* gp = Wfp + (size_t)c * EMB + k0 + ck;
                    float4 a = ((const float4*)gp)[0];
                    float4 b = ((const float4*)gp)[1];
                    v[0] = (short)f2bf(a.x); v[1] = (short)f2bf(a.y);
                    v[2] = (short)f2bf(a.z); v[3] = (short)f2bf(a.w);
                    v[4] = (short)f2bf(b.x); v[5] = (short)f2bf(b.y);
                    v[6] = (short)f2bf(b.z); v[7] = (short)f2bf(b.w);
                }
                *(bf16x8*)(&Bs[row][ck]) = v;
            }
        }
        __syncthreads();
        // ---- compute: 2 x (4x4) MFMA 16x16x32 ----
        #pragma unroll
        for (int kk = 0; kk < 2; ++kk) {
            const int ko = kk * 32 + ((lane >> 4) << 3);
            bf16x8 af[4], bw[4];
            #pragma unroll
            for (int m = 0; m < 4; ++m)
                af[m] = *(const bf16x8*)(&As[wr * 64 + m * 16 + (lane & 15)][ko]);
            #pragma unroll
            for (int n = 0; n < 4; ++n)
                bw[n] = *(const bf16x8*)(&Bs[wc * 64 + n * 16 + (lane & 15)][ko]);
            #pragma unroll
            for (int m = 0; m < 4; ++m)
                #pragma unroll
                for (int n = 0; n < 4; ++n)
                    acc[m][n] = __builtin_amdgcn_mfma_f32_16x16x32_bf16(
                        af[m], bw[n], acc[m][n], 0, 0, 0);
        }
    }

    // ---- epilogue: store, label-column uses precomputed exact phi value,
    //      per-row (max, sumexp) partials ----
    const int q = lane >> 4, fr = lane & 15;
    const int jcol = (nblk << 1) | wc;
    #pragma unroll
    for (int m = 0; m < 4; ++m) {
        #pragma unroll
        for (int j = 0; j < 4; ++j) {
            const int grow = m0 + wr * 64 + m * 16 + q * 4 + j;
            const int lab = label[grow];
            const float exv = exact_val[grow];
            float o[4]; int cc[4];
            float vmax = -1e30f;
            #pragma unroll
            for (int n = 0; n < 4; ++n) {
                const int col = c0 + wc * 64 + n * 16 + fr;   // < CPAD always
                float cosv = acc[m][n][j];
                if (BSRC == 1) cosv *= inv_norm[col];
                float val = (col == lab) ? exv : (S_F * cosv);
                o[n] = val; cc[n] = col;
                if (col < NCLS) {
                    out[(size_t)grow * NCLS + col] = val;
                    vmax = fmaxf(vmax, val);
                }
            }
            #pragma unroll
            for (int msk = 1; msk < 16; msk <<= 1)
                vmax = fmaxf(vmax, __shfl_xor(vmax, msk));
            float vsum = 0.0f;
            #pragma unroll
            for (int n = 0; n < 4; ++n)
                if (cc[n] < NCLS) vsum += __expf(o[n] - vmax);
            #pragma unroll
            for (int msk = 1; msk < 16; msk <<= 1)
                vsum += __shfl_xor(vsum, msk);
            if (fr == 0) {
                pmax[(size_t)grow * NJ + jcol] = vmax;
                psum[(size_t)grow * NJ + jcol] = vsum;
            }
        }
    }
}

// ---------------- K3: per-row lse + nll ----------------
__global__ __launch_bounds__(256) void row_lse_kernel(
    const float* __restrict__ pmax, const float* __restrict__ psum,
    const float* __restrict__ out, const int* __restrict__ label,
    float* __restrict__ nll) {
    const int row = blockIdx.x;
    const int t = threadIdx.x;
    float m = -1e30f, s = 0.f;
    for (int j = t; j < NJ; j += 256) {
        float pm = pmax[(size_t)row * NJ + j];
        float ps = psum[(size_t)row * NJ + j];
        float nm = fmaxf(m, pm);
        s = s * __expf(m - nm) + ps * __expf(pm - nm);
        m = nm;
    }
    #pragma unroll
    for (int msk = 1; msk < 64; msk <<= 1) {
        float om = __shfl_xor(m, msk), os = __shfl_xor(s, msk);
        float nm = fmaxf(m, om);
        s = s * __expf(m - nm) + os * __expf(om - nm);
        m = nm;
    }
    __shared__ float sm[4], ss[4];
    const int lane = t & 63, wid = t >> 6;
    if (lane == 0) { sm[wid] = m; ss[wid] = s; }
    __syncthreads();
    if (t == 0) {
        float M = sm[0], SS = ss[0];
        #pragma unroll
        for (int w = 1; w < 4; ++w) {
            float nm = fmaxf(M, sm[w]);
            SS = SS * __expf(M - nm) + ss[w] * __expf(sm[w] - nm);
            M = nm;
        }
        float lse = M + logf(SS);
        float tgt = out[(size_t)row * NCLS + label[row]];
        nll[row] = lse - tgt;
    }
}

// ---------------- K4: mean loss ----------------
__global__ __launch_bounds__(512) void loss_kernel(
    const float* __restrict__ nll, float* __restrict__ out_loss) {
    const int t = threadIdx.x;   // 512 threads
    float v = nll[t];
    #pragma unroll
    for (int msk = 1; msk < 64; msk <<= 1) v += __shfl_xor(v, msk);
    __shared__ float sv[8];
    if ((t & 63) == 0) sv[t >> 6] = v;
    __syncthreads();
    if (t == 0) {
        float s = 0.f;
        #pragma unroll
        for (int w = 0; w < 8; ++w) s += sv[w];
        out_loss[0] = s / 512.0f;
    }
}

// ---------------- host ----------------
extern "C" void kernel_launch(void* const* d_in, const int* in_sizes, int n_in,
                              void* d_out, int out_size, void* d_ws, size_t ws_size,
                              hipStream_t stream) {
    const float* input  = (const float*)d_in[0];
    const int*   label  = (const int*)d_in[1];
    const float* weight = (const float*)d_in[2];
    float* out = (float*)d_out;
    char* ws = (char*)d_ws;
    ushort_t* Abf     = (ushort_t*)(ws + WS_ABF);
    float*    invn    = (float*)(ws + WS_INV);
    float*    pmax    = (float*)(ws + WS_PMAX);
    float*    psum    = (float*)(ws + WS_PSUM);
    float*    nll     = (float*)(ws + WS_NLL);
    float*    exv     = (float*)(ws + WS_EXACT);
    ushort_t* Wbf     = (ushort_t*)(ws + WS_WBF);
    const bool fast = ws_size >= WS_NEED_FAST;

    cvt_input_kernel<<<dim3(256), dim3(256), 0, stream>>>(input, Abf);
    if (fast) {
        norms_kernel<true><<<dim3(CPAD / 4), dim3(256), 0, stream>>>(weight, Wbf, invn);
        exact_label_kernel<<<dim3(128), dim3(256), 0, stream>>>(input, weight, invn, label, exv);
        gemm_kernel<0><<<dim3(4 * NBN), dim3(256), 0, stream>>>(
            Abf, weight, Wbf, invn, label, exv, out, pmax, psum);
    } else {
        norms_kernel<false><<<dim3(CPAD / 4), dim3(256), 0, stream>>>(weight, Wbf, invn);
        exact_label_kernel<<<dim3(128), dim3(256), 0, stream>>>(input, weight, invn, label, exv);
        gemm_kernel<1><<<dim3(4 * NBN), dim3(256), 0, stream>>>(
            Abf, weight, Wbf, invn, label, exv, out, pmax, psum);
    }
    row_lse_kernel<<<dim3(512), dim3(256), 0, stream>>>(pmax, psum, out, label, nll);
    loss_kernel<<<dim3(1), dim3(512), 0, stream>>>(nll, out + (out_size - 1));
}

// Round 3
// 510.633 us; speedup vs baseline: 1.0062x; 1.0062x over previous
//
#include <hip/hip_runtime.h>

// ---------------- problem constants ----------------
#define NCLS   100000
#define CPAD   100096          // 782 * 128
#define EMB    512
#define BATCH  512
#define NBN    782             // N tiles of 128
#define NJ     1564            // NBN * 2 (per-wave-column lse partials)

#define S_F     64.0f
#define COS_M_F 0.8775825619f   // cos(0.5)
#define SIN_M_F 0.4794255386f   // sin(0.5)
#define TH_F   (-0.8775825619f) // cos(pi-0.5)
#define MM_F    0.2397127693f   // sin(pi-0.5)*0.5

// ws layout (bytes)
#define WS_ABF   0ull                      // 512*512 bf16   = 524288
#define WS_PMAX  524288ull                 // 512*NJ f32     = 3203072
#define WS_PSUM  3727360ull                // 512*NJ f32     = 3203072
#define WS_NLL   6930432ull                // 512 f32        = 2048
#define WS_EXACT 6932480ull                // 512 f32        = 2048
#define WS_INV   6934528ull                // CPAD f32       = 400384
#define WS_WBF   7334912ull                // chunked bf16 weight panel (16B aligned)

typedef unsigned short ushort_t;
typedef __attribute__((ext_vector_type(8))) short bf16x8;
typedef __attribute__((ext_vector_type(4))) float floatx4;

__device__ __forceinline__ unsigned short f2bf(float f) {
    union { float f; unsigned int u; } c; c.f = f;
    unsigned int r = c.u + 0x7FFFu + ((c.u >> 16) & 1u);   // RNE
    return (unsigned short)(r >> 16);
}

__device__ __forceinline__ void load_lds16(const void* g, void* l) {
    __builtin_amdgcn_global_load_lds(
        (const __attribute__((address_space(1))) void*)g,
        (__attribute__((address_space(3))) void*)l, 16, 0, 0);
}

// m204 bijective XCD swizzle: contiguous logical chunk per XCD
__device__ __forceinline__ int xcd_swizzle(int b0, int nwg) {
    const int q = nwg >> 3, r = nwg & 7;
    const int x = b0 & 7, o = b0 >> 3;
    const int base = (x < r) ? x * (q + 1) : r * (q + 1) + (x - r) * q;
    return base + o;
}

// ---------------- K0: input fp32 -> bf16 ----------------
__global__ __launch_bounds__(256) void cvt_input_kernel(
    const float* __restrict__ in, ushort_t* __restrict__ Abf) {
    int gid = blockIdx.x * 256 + threadIdx.x;          // 65536 threads, 4 elems each
    float4 f = ((const float4*)in)[gid];
    uint2 u;
    u.x = (unsigned)f2bf(f.x) | ((unsigned)f2bf(f.y) << 16);
    u.y = (unsigned)f2bf(f.z) | ((unsigned)f2bf(f.w) << 16);
    ((uint2*)Abf)[gid] = u;
}

// ---------------- K1: exact fp32 label-column cosine + phi (self-normed) ----------
__global__ __launch_bounds__(256) void exact_label_kernel(
    const float* __restrict__ input, const float* __restrict__ W,
    const int* __restrict__ label, float* __restrict__ exact_val) {
    const int t = threadIdx.x;
    const int lane = t & 63;
    const int row = blockIdx.x * 4 + (t >> 6);         // 128 blocks x 4 waves
    const int lab = label[row];
    const float4* ip = (const float4*)(input + (size_t)row * EMB);
    const float4* wp = (const float4*)(W + (size_t)lab * EMB);
    float4 a0 = ip[lane], a1 = ip[64 + lane];
    float4 b0 = wp[lane], b1 = wp[64 + lane];
    float dot = a0.x*b0.x + a0.y*b0.y + a0.z*b0.z + a0.w*b0.w
              + a1.x*b1.x + a1.y*b1.y + a1.z*b1.z + a1.w*b1.w;
    float ssq = b0.x*b0.x + b0.y*b0.y + b0.z*b0.z + b0.w*b0.w
              + b1.x*b1.x + b1.y*b1.y + b1.z*b1.z + b1.w*b1.w;
    #pragma unroll
    for (int msk = 1; msk < 64; msk <<= 1) {
        dot += __shfl_xor(dot, msk);
        ssq += __shfl_xor(ssq, msk);
    }
    if (lane == 0) {
        float c = dot / fmaxf(sqrtf(ssq), 1e-12f);
        float sine = sqrtf(fmaxf(1.0f - c * c, 0.0f));
        float phi = c * COS_M_F - sine * SIN_M_F;
        phi = (c > TH_F) ? phi : (c - MM_F);
        exact_val[row] = S_F * phi;
    }
}

// ---------------- K2a: normalized bf16 weight chunk ----------------
__global__ __launch_bounds__(256) void norms_chunk_kernel(
    const float* __restrict__ W, ushort_t* __restrict__ Wbfc, int cls0) {
    const int t = threadIdx.x, lane = t & 63;
    const int rl = blockIdx.x * 4 + (t >> 6);          // local row in chunk
    const int r = cls0 + rl;
    float4 f0 = make_float4(0.f, 0.f, 0.f, 0.f);
    float4 f1 = make_float4(0.f, 0.f, 0.f, 0.f);
    float ssq = 0.f;
    if (r < NCLS) {
        const float4* rp = (const float4*)(W + (size_t)r * EMB);
        f0 = rp[lane * 2];
        f1 = rp[lane * 2 + 1];
        ssq = f0.x*f0.x + f0.y*f0.y + f0.z*f0.z + f0.w*f0.w
            + f1.x*f1.x + f1.y*f1.y + f1.z*f1.z + f1.w*f1.w;
    }
    #pragma unroll
    for (int msk = 1; msk < 64; msk <<= 1) ssq += __shfl_xor(ssq, msk);
    float inv = 0.f;
    if (r < NCLS) inv = 1.0f / fmaxf(sqrtf(ssq), 1e-12f);
    uint4 u;
    u.x = (unsigned)f2bf(f0.x*inv) | ((unsigned)f2bf(f0.y*inv) << 16);
    u.y = (unsigned)f2bf(f0.z*inv) | ((unsigned)f2bf(f0.w*inv) << 16);
    u.z = (unsigned)f2bf(f1.x*inv) | ((unsigned)f2bf(f1.y*inv) << 16);
    u.w = (unsigned)f2bf(f1.z*inv) | ((unsigned)f2bf(f1.w*inv) << 16);
    ((uint4*)(Wbfc + (size_t)rl * EMB))[lane] = u;
}

// ---------------- K2b: inv-norm only (fallback) ----------------
__global__ __launch_bounds__(256) void norms_inv_kernel(
    const float* __restrict__ W, float* __restrict__ inv_norm) {
    const int t = threadIdx.x, lane = t & 63;
    const int r = blockIdx.x * 4 + (t >> 6);
    float ssq = 0.f;
    if (r < NCLS) {
        const float4* rp = (const float4*)(W + (size_t)r * EMB);
        float4 f0 = rp[lane * 2], f1 = rp[lane * 2 + 1];
        ssq = f0.x*f0.x + f0.y*f0.y + f0.z*f0.z + f0.w*f0.w
            + f1.x*f1.x + f1.y*f1.y + f1.z*f1.z + f1.w*f1.w;
    }
    #pragma unroll
    for (int msk = 1; msk < 64; msk <<= 1) ssq += __shfl_xor(ssq, msk);
    if (lane == 0 && r < CPAD)
        inv_norm[r] = (r < NCLS) ? 1.0f / fmaxf(sqrtf(ssq), 1e-12f) : 0.f;
}

// ---------------- K3: GEMM + arcface epilogue + lse partials ----------------
// LDS tiles [128 rows][8 slots of 8 bf16], XOR-swizzled: LDS[row][p] holds
// logical slot p^(row&7). Stage: linear gload_lds dest + swizzled global src.
// Read: ds_read_b128 at slot (lslot^(row&7)) -> conflict-free (2/bank per quarter).
template <int BSRC>
__global__ __launch_bounds__(256) void gemm_kernel(
    const ushort_t* __restrict__ Abf,   // [512][512] bf16
    const float*    __restrict__ Wfp,   // [NCLS][512] fp32 (BSRC==1)
    const ushort_t* __restrict__ Wbfc,  // chunk [per*128][512] bf16 normalized (BSRC==0)
    const float*    __restrict__ inv_norm,
    const int*      __restrict__ label,
    const float*    __restrict__ exact_val,
    float*          __restrict__ out,   // [512][NCLS]
    float* __restrict__ pmax, float* __restrict__ psum,
    int nblk0) {
    __shared__ ushort_t As[128 * 64];
    __shared__ ushort_t Bs[128 * 64];

    const int t = threadIdx.x;
    const int lane = t & 63, wid = t >> 6;
    const int wr = wid >> 1, wc = wid & 1;            // 2x2 waves, each 64x64 out
    const int wg = xcd_swizzle(blockIdx.x, gridDim.x);
    const int mblk = wg & 3, nblkL = wg >> 2;
    const int m0 = mblk * 128;
    const int nblk = nblk0 + nblkL;
    const int c0 = nblk * 128;

    floatx4 acc[4][4] = {};

    for (int k0 = 0; k0 < EMB; k0 += 64) {
        __syncthreads();
        // ---- stage A: linear LDS dest, inverse-swizzled global source col ----
        #pragma unroll
        for (int r = 0; r < 4; ++r) {
            const int i = r * 256 + t;                 // 16B chunk id in tile
            const int row = i >> 3;
            const int ls = (i & 7) ^ (row & 7);        // logical slot for this dest
            const ushort_t* gp = Abf + (size_t)(m0 + row) * EMB + k0 + (ls << 3);
            load_lds16(gp, (char*)As + (size_t)(r * 256 + wid * 64) * 16);
        }
        // ---- stage B ----
        if constexpr (BSRC == 0) {
            #pragma unroll
            for (int r = 0; r < 4; ++r) {
                const int i = r * 256 + t;
                const int row = i >> 3;
                const int ls = (i & 7) ^ (row & 7);
                const ushort_t* gp = Wbfc + (size_t)(nblkL * 128 + row) * EMB + k0 + (ls << 3);
                load_lds16(gp, (char*)Bs + (size_t)(r * 256 + wid * 64) * 16);
            }
        } else {
            #pragma unroll
            for (int r = 0; r < 4; ++r) {
                const int i = r * 256 + t;
                const int row = i >> 3;
                const int ls = i & 7;                  // handle logical slot ls
                const int c = c0 + row;
                bf16x8 v = {0, 0, 0, 0, 0, 0, 0, 0};
                if (c < NCLS) {
                    const float* gp = Wfp + (size_t)c * EMB + k0 + (ls << 3);
                    float4 a = ((const float4*)gp)[0];
                    float4 b = ((const float4*)gp)[1];
                    v[0] = (short)f2bf(a.x); v[1] = (short)f2bf(a.y);
                    v[2] = (short)f2bf(a.z); v[3] = (short)f2bf(a.w);
                    v[4] = (short)f2bf(b.x); v[5] = (short)f2bf(b.y);
                    v[6] = (short)f2bf(b.z); v[7] = (short)f2bf(b.w);
                }
                *(bf16x8*)((char*)Bs + (size_t)row * 128 + ((ls ^ (row & 7)) << 4)) = v;
            }
        }
        __syncthreads();
        // ---- compute: 2 x (4x4) MFMA 16x16x32, swizzled ds_read ----
        const int fr = lane & 15, q = lane >> 4, sx = fr & 7;
        #pragma unroll
        for (int kk = 0; kk < 2; ++kk) {
            const int lslot = kk * 4 + q;
            bf16x8 af[4], bw[4];
            #pragma unroll
            for (int m = 0; m < 4; ++m) {
                const int row = wr * 64 + m * 16 + fr;
                af[m] = *(const bf16x8*)((const char*)As + (size_t)row * 128 + ((lslot ^ sx) << 4));
            }
            #pragma unroll
            for (int n = 0; n < 4; ++n) {
                const int row = wc * 64 + n * 16 + fr;
                bw[n] = *(const bf16x8*)((const char*)Bs + (size_t)row * 128 + ((lslot ^ sx) << 4));
            }
            #pragma unroll
            for (int m = 0; m < 4; ++m)
                #pragma unroll
                for (int n = 0; n < 4; ++n)
                    acc[m][n] = __builtin_amdgcn_mfma_f32_16x16x32_bf16(
                        af[m], bw[n], acc[m][n], 0, 0, 0);
        }
    }

    // ---- epilogue: nontemporal store; label col uses exact fp32 phi;
    //      per-row (max, sumexp) partials ----
    const int fr = lane & 15, q = lane >> 4;
    const int jcol = (nblk << 1) | wc;
    #pragma unroll
    for (int m = 0; m < 4; ++m) {
        #pragma unroll
        for (int j = 0; j < 4; ++j) {
            const int grow = m0 + wr * 64 + m * 16 + q * 4 + j;
            const int lab = label[grow];
            const float exv = exact_val[grow];
            float o[4]; int cc[4];
            float vmax = -1e30f;
            #pragma unroll
            for (int n = 0; n < 4; ++n) {
                const int col = c0 + wc * 64 + n * 16 + fr;   // < CPAD always
                float cosv = acc[m][n][j];
                if (BSRC == 1) cosv *= inv_norm[col];
                float val = (col == lab) ? exv : (S_F * cosv);
                o[n] = val; cc[n] = col;
                if (col < NCLS) {
                    __builtin_nontemporal_store(val, &out[(size_t)grow * NCLS + col]);
                    vmax = fmaxf(vmax, val);
                }
            }
            #pragma unroll
            for (int msk = 1; msk < 16; msk <<= 1)
                vmax = fmaxf(vmax, __shfl_xor(vmax, msk));
            float vsum = 0.0f;
            #pragma unroll
            for (int n = 0; n < 4; ++n)
                if (cc[n] < NCLS) vsum += __expf(o[n] - vmax);
            #pragma unroll
            for (int msk = 1; msk < 16; msk <<= 1)
                vsum += __shfl_xor(vsum, msk);
            if (fr == 0) {
                pmax[(size_t)grow * NJ + jcol] = vmax;
                psum[(size_t)grow * NJ + jcol] = vsum;
            }
        }
    }
}

// ---------------- K4: per-row lse + nll ----------------
__global__ __launch_bounds__(256) void row_lse_kernel(
    const float* __restrict__ pmax, const float* __restrict__ psum,
    const float* __restrict__ out, const int* __restrict__ label,
    float* __restrict__ nll) {
    const int row = blockIdx.x;
    const int t = threadIdx.x;
    float m = -1e30f, s = 0.f;
    for (int j = t; j < NJ; j += 256) {
        float pm = pmax[(size_t)row * NJ + j];
        float ps = psum[(size_t)row * NJ + j];
        float nm = fmaxf(m, pm);
        s = s * __expf(m - nm) + ps * __expf(pm - nm);
        m = nm;
    }
    #pragma unroll
    for (int msk = 1; msk < 64; msk <<= 1) {
        float om = __shfl_xor(m, msk), os = __shfl_xor(s, msk);
        float nm = fmaxf(m, om);
        s = s * __expf(m - nm) + os * __expf(om - nm);
        m = nm;
    }
    __shared__ float sm[4], ss[4];
    const int lane = t & 63, wid = t >> 6;
    if (lane == 0) { sm[wid] = m; ss[wid] = s; }
    __syncthreads();
    if (t == 0) {
        float M = sm[0], SS = ss[0];
        #pragma unroll
        for (int w = 1; w < 4; ++w) {
            float nm = fmaxf(M, sm[w]);
            SS = SS * __expf(M - nm) + ss[w] * __expf(sm[w] - nm);
            M = nm;
        }
        float lse = M + logf(SS);
        float tgt = out[(size_t)row * NCLS + label[row]];
        nll[row] = lse - tgt;
    }
}

// ---------------- K5: mean loss ----------------
__global__ __launch_bounds__(512) void loss_kernel(
    const float* __restrict__ nll, float* __restrict__ out_loss) {
    const int t = threadIdx.x;   // 512 threads
    float v = nll[t];
    #pragma unroll
    for (int msk = 1; msk < 64; msk <<= 1) v += __shfl_xor(v, msk);
    __shared__ float sv[8];
    if ((t & 63) == 0) sv[t >> 6] = v;
    __syncthreads();
    if (t == 0) {
        float s = 0.f;
        #pragma unroll
        for (int w = 0; w < 8; ++w) s += sv[w];
        out_loss[0] = s / 512.0f;
    }
}

// ---------------- host ----------------
extern "C" void kernel_launch(void* const* d_in, const int* in_sizes, int n_in,
                              void* d_out, int out_size, void* d_ws, size_t ws_size,
                              hipStream_t stream) {
    const float* input  = (const float*)d_in[0];
    const int*   label  = (const int*)d_in[1];
    const float* weight = (const float*)d_in[2];
    float* out = (float*)d_out;
    char* ws = (char*)d_ws;
    ushort_t* Abf  = (ushort_t*)(ws + WS_ABF);
    float*    pmax = (float*)(ws + WS_PMAX);
    float*    psum = (float*)(ws + WS_PSUM);
    float*    nll  = (float*)(ws + WS_NLL);
    float*    exv  = (float*)(ws + WS_EXACT);
    float*    invn = (float*)(ws + WS_INV);
    ushort_t* Wbf  = (ushort_t*)(ws + WS_WBF);

    // pick smallest chunk count whose bf16 weight panel fits in remaining ws
    size_t avail = ws_size > WS_WBF ? ws_size - WS_WBF : 0;
    int nch = 0, per = 0;
    const int cand[5] = {1, 2, 4, 8, 16};
    for (int ci = 0; ci < 5; ++ci) {
        int p = (NBN + cand[ci] - 1) / cand[ci];
        if ((size_t)p * 128 * EMB * 2 <= avail) { nch = cand[ci]; per = p; break; }
    }

    cvt_input_kernel<<<dim3(256), dim3(256), 0, stream>>>(input, Abf);
    exact_label_kernel<<<dim3(128), dim3(256), 0, stream>>>(input, weight, label, exv);

    if (nch) {
        for (int c = 0; c < nch; ++c) {
            const int nb0 = c * per;
            int pc = NBN - nb0; if (pc > per) pc = per;
            if (pc <= 0) break;
            norms_chunk_kernel<<<dim3(pc * 32), dim3(256), 0, stream>>>(
                weight, Wbf, nb0 * 128);
            gemm_kernel<0><<<dim3(4 * pc), dim3(256), 0, stream>>>(
                Abf, weight, Wbf, invn, label, exv, out, pmax, psum, nb0);
        }
    } else {
        norms_inv_kernel<<<dim3(CPAD / 4), dim3(256), 0, stream>>>(weight, invn);
        gemm_kernel<1><<<dim3(4 * NBN), dim3(256), 0, stream>>>(
            Abf, weight, Wbf, invn, label, exv, out, pmax, psum, 0);
    }
    row_lse_kernel<<<dim3(512), dim3(256), 0, stream>>>(pmax, psum, out, label, nll);
    loss_kernel<<<dim3(1), dim3(512), 0, stream>>>(nll, out + (out_size - 1));
}

// Round 5
// 485.105 us; speedup vs baseline: 1.0592x; 1.0526x over previous
//
#include <hip/hip_runtime.h>

// ---------------- problem constants ----------------
#define NCLS   100000
#define CPAD   100096          // 782 * 128
#define EMB    512
#define BATCH  512
#define NBN    782             // N tiles of 128
#define NJ     1564            // NBN * 2 (per-wave-column lse partials)

#define S_F     64.0f
#define COS_M_F 0.8775825619f   // cos(0.5)
#define SIN_M_F 0.4794255386f   // sin(0.5)
#define TH_F   (-0.8775825619f) // cos(pi-0.5)
#define MM_F    0.2397127693f   // sin(pi-0.5)*0.5

// ws layout (bytes)
#define WS_ABF   0ull                      // 512*512 bf16   = 524288
#define WS_PMAX  524288ull                 // NJ*512 f32     = 3203072  (transposed: [jcol][row])
#define WS_PSUM  3727360ull                // NJ*512 f32     = 3203072
#define WS_NLL   6930432ull                // 512 f32        = 2048
#define WS_EXACT 6932480ull                // 512 f32        = 2048
#define WS_INV   6934528ull                // CPAD f32       = 400384
#define WS_WBF   7334912ull                // chunked bf16 weight panel (16B aligned)

typedef unsigned short ushort_t;
typedef __attribute__((ext_vector_type(8))) short bf16x8;
typedef __attribute__((ext_vector_type(4))) float floatx4;

__device__ __forceinline__ unsigned short f2bf(float f) {
    union { float f; unsigned int u; } c; c.f = f;
    unsigned int r = c.u + 0x7FFFu + ((c.u >> 16) & 1u);   // RNE
    return (unsigned short)(r >> 16);
}

__device__ __forceinline__ void load_lds16(const void* g, void* l) {
    __builtin_amdgcn_global_load_lds(
        (const __attribute__((address_space(1))) void*)g,
        (__attribute__((address_space(3))) void*)l, 16, 0, 0);
}

// m204 bijective XCD swizzle: contiguous logical chunk per XCD
__device__ __forceinline__ int xcd_swizzle(int b0, int nwg) {
    const int q = nwg >> 3, r = nwg & 7;
    const int x = b0 & 7, o = b0 >> 3;
    const int base = (x < r) ? x * (q + 1) : r * (q + 1) + (x - r) * q;
    return base + o;
}

// ---------------- K0: input fp32 -> bf16 ----------------
__global__ __launch_bounds__(256) void cvt_input_kernel(
    const float* __restrict__ in, ushort_t* __restrict__ Abf) {
    int gid = blockIdx.x * 256 + threadIdx.x;          // 65536 threads, 4 elems each
    float4 f = ((const float4*)in)[gid];
    uint2 u;
    u.x = (unsigned)f2bf(f.x) | ((unsigned)f2bf(f.y) << 16);
    u.y = (unsigned)f2bf(f.z) | ((unsigned)f2bf(f.w) << 16);
    ((uint2*)Abf)[gid] = u;
}

// ---------------- K1: exact fp32 label-column cosine + phi (self-normed) ----------
__global__ __launch_bounds__(256) void exact_label_kernel(
    const float* __restrict__ input, const float* __restrict__ W,
    const int* __restrict__ label, float* __restrict__ exact_val) {
    const int t = threadIdx.x;
    const int lane = t & 63;
    const int row = blockIdx.x * 4 + (t >> 6);         // 128 blocks x 4 waves
    const int lab = label[row];
    const float4* ip = (const float4*)(input + (size_t)row * EMB);
    const float4* wp = (const float4*)(W + (size_t)lab * EMB);
    float4 a0 = ip[lane], a1 = ip[64 + lane];
    float4 b0 = wp[lane], b1 = wp[64 + lane];
    float dot = a0.x*b0.x + a0.y*b0.y + a0.z*b0.z + a0.w*b0.w
              + a1.x*b1.x + a1.y*b1.y + a1.z*b1.z + a1.w*b1.w;
    float ssq = b0.x*b0.x + b0.y*b0.y + b0.z*b0.z + b0.w*b0.w
              + b1.x*b1.x + b1.y*b1.y + b1.z*b1.z + b1.w*b1.w;
    #pragma unroll
    for (int msk = 1; msk < 64; msk <<= 1) {
        dot += __shfl_xor(dot, msk);
        ssq += __shfl_xor(ssq, msk);
    }
    if (lane == 0) {
        float c = dot / fmaxf(sqrtf(ssq), 1e-12f);
        float sine = sqrtf(fmaxf(1.0f - c * c, 0.0f));
        float phi = c * COS_M_F - sine * SIN_M_F;
        phi = (c > TH_F) ? phi : (c - MM_F);
        exact_val[row] = S_F * phi;
    }
}

// ---------------- K2a: normalized bf16 weight chunk ----------------
__global__ __launch_bounds__(256) void norms_chunk_kernel(
    const float* __restrict__ W, ushort_t* __restrict__ Wbfc, int cls0) {
    const int t = threadIdx.x, lane = t & 63;
    const int rl = blockIdx.x * 4 + (t >> 6);          // local row in chunk
    const int r = cls0 + rl;
    float4 f0 = make_float4(0.f, 0.f, 0.f, 0.f);
    float4 f1 = make_float4(0.f, 0.f, 0.f, 0.f);
    float ssq = 0.f;
    if (r < NCLS) {
        const float4* rp = (const float4*)(W + (size_t)r * EMB);
        f0 = rp[lane * 2];
        f1 = rp[lane * 2 + 1];
        ssq = f0.x*f0.x + f0.y*f0.y + f0.z*f0.z + f0.w*f0.w
            + f1.x*f1.x + f1.y*f1.y + f1.z*f1.z + f1.w*f1.w;
    }
    #pragma unroll
    for (int msk = 1; msk < 64; msk <<= 1) ssq += __shfl_xor(ssq, msk);
    float inv = 0.f;
    if (r < NCLS) inv = 1.0f / fmaxf(sqrtf(ssq), 1e-12f);
    uint4 u;
    u.x = (unsigned)f2bf(f0.x*inv) | ((unsigned)f2bf(f0.y*inv) << 16);
    u.y = (unsigned)f2bf(f0.z*inv) | ((unsigned)f2bf(f0.w*inv) << 16);
    u.z = (unsigned)f2bf(f1.x*inv) | ((unsigned)f2bf(f1.y*inv) << 16);
    u.w = (unsigned)f2bf(f1.z*inv) | ((unsigned)f2bf(f1.w*inv) << 16);
    ((uint4*)(Wbfc + (size_t)rl * EMB))[lane] = u;
}

// ---------------- K2b: inv-norm only (fallback) ----------------
__global__ __launch_bounds__(256) void norms_inv_kernel(
    const float* __restrict__ W, float* __restrict__ inv_norm) {
    const int t = threadIdx.x, lane = t & 63;
    const int r = blockIdx.x * 4 + (t >> 6);
    float ssq = 0.f;
    if (r < NCLS) {
        const float4* rp = (const float4*)(W + (size_t)r * EMB);
        float4 f0 = rp[lane * 2], f1 = rp[lane * 2 + 1];
        ssq = f0.x*f0.x + f0.y*f0.y + f0.z*f0.z + f0.w*f0.w
            + f1.x*f1.x + f1.y*f1.y + f1.z*f1.z + f1.w*f1.w;
    }
    #pragma unroll
    for (int msk = 1; msk < 64; msk <<= 1) ssq += __shfl_xor(ssq, msk);
    if (lane == 0 && r < CPAD)
        inv_norm[r] = (r < NCLS) ? 1.0f / fmaxf(sqrtf(ssq), 1e-12f) : 0.f;
}

// ---------------- K3: GEMM + arcface epilogue + lse partials ----------------
// Double-buffered LDS, prefetch-before-compute 2-phase loop (T3 minimum recipe):
//   STAGE(next tile) -> sched_barrier -> ds_read+MFMA(cur, setprio) -> barrier
// LDS tiles [128 rows][8 slots of 8 bf16], XOR-swizzled (T2), staged via
// linear gload_lds dest + inverse-swizzled global source column.
// Plain (cached) stores: nt stores caused ~2.3x write amplification (r3 PMC).
template <int BSRC>
__global__ __launch_bounds__(256, 2) void gemm_kernel(
    const ushort_t* __restrict__ Abf,   // [512][512] bf16
    const float*    __restrict__ Wfp,   // [NCLS][512] fp32 (BSRC==1)
    const ushort_t* __restrict__ Wbfc,  // chunk [per*128][512] bf16 normalized (BSRC==0)
    const float*    __restrict__ inv_norm,
    const int*      __restrict__ label,
    const float*    __restrict__ exact_val,
    float*          __restrict__ out,   // [512][NCLS]
    float* __restrict__ pmax, float* __restrict__ psum,
    int nblk0) {
    __shared__ ushort_t As[2][128 * 64];
    __shared__ ushort_t Bs[2][128 * 64];

    const int t = threadIdx.x;
    const int lane = t & 63, wid = t >> 6;
    const int wr = wid >> 1, wc = wid & 1;            // 2x2 waves, each 64x64 out
    const int wg = xcd_swizzle(blockIdx.x, gridDim.x);
    const int mblk = wg & 3, nblkL = wg >> 2;
    const int m0 = mblk * 128;
    const int nblk = nblk0 + nblkL;
    const int c0 = nblk * 128;

    floatx4 acc[4][4] = {};

    // ---- staging helpers ----
    auto stageA = [&](int buf, int k0) {
        #pragma unroll
        for (int r = 0; r < 4; ++r) {
            const int i = r * 256 + t;                 // 16B chunk id in tile
            const int row = i >> 3;
            const int ls = (i & 7) ^ (row & 7);        // inverse-swizzled source slot
            load_lds16(Abf + (size_t)(m0 + row) * EMB + k0 + (ls << 3),
                       (char*)As[buf] + (size_t)(r * 256 + wid * 64) * 16);
        }
    };
    auto stageB0 = [&](int buf, int k0) {
        #pragma unroll
        for (int r = 0; r < 4; ++r) {
            const int i = r * 256 + t;
            const int row = i >> 3;
            const int ls = (i & 7) ^ (row & 7);
            load_lds16(Wbfc + (size_t)(nblkL * 128 + row) * EMB + k0 + (ls << 3),
                       (char*)Bs[buf] + (size_t)(r * 256 + wid * 64) * 16);
        }
    };
    auto stageB1 = [&](int buf, int k0) {
        #pragma unroll
        for (int r = 0; r < 4; ++r) {
            const int i = r * 256 + t;
            const int row = i >> 3;
            const int ls = i & 7;                      // logical slot handled
            const int c = c0 + row;
            bf16x8 v = {0, 0, 0, 0, 0, 0, 0, 0};
            if (c < NCLS) {
                const float* gp = Wfp + (size_t)c * EMB + k0 + (ls << 3);
                float4 a = ((const float4*)gp)[0];
                float4 b = ((const float4*)gp)[1];
                v[0] = (short)f2bf(a.x); v[1] = (short)f2bf(a.y);
                v[2] = (short)f2bf(a.z); v[3] = (short)f2bf(a.w);
                v[4] = (short)f2bf(b.x); v[5] = (short)f2bf(b.y);
                v[6] = (short)f2bf(b.z); v[7] = (short)f2bf(b.w);
            }
            *(bf16x8*)((char*)Bs[buf] + (size_t)row * 128 + ((ls ^ (row & 7)) << 4)) = v;
        }
    };

    // ---- prologue: stage K-tile 0 into buf 0 ----
    stageA(0, 0);
    if constexpr (BSRC == 0) stageB0(0, 0); else stageB1(0, 0);
    __syncthreads();                                   // implicit vmcnt(0)+lgkmcnt(0)

    const int fr0 = lane & 15, q0 = lane >> 4, sx = fr0 & 7;

    for (int kt = 0; kt < 8; ++kt) {
        const int cur = kt & 1;
        // ---- issue next-tile stage first (overlaps with compute below) ----
        if (kt < 7) {
            stageA(cur ^ 1, (kt + 1) * 64);
            if constexpr (BSRC == 0) stageB0(cur ^ 1, (kt + 1) * 64);
            else                     stageB1(cur ^ 1, (kt + 1) * 64);
        }
        __builtin_amdgcn_sched_barrier(0);             // pin stage-issue before reads
        // ---- compute current tile: 2 x (4x4) MFMA 16x16x32, swizzled ds_read ----
        const char* Ab = (const char*)As[cur];
        const char* Bb = (const char*)Bs[cur];
        #pragma unroll
        for (int kk = 0; kk < 2; ++kk) {
            const int lslot = kk * 4 + q0;
            bf16x8 af[4], bw[4];
            #pragma unroll
            for (int m = 0; m < 4; ++m) {
                const int row = wr * 64 + m * 16 + fr0;
                af[m] = *(const bf16x8*)(Ab + (size_t)row * 128 + ((lslot ^ sx) << 4));
            }
            #pragma unroll
            for (int n = 0; n < 4; ++n) {
                const int row = wc * 64 + n * 16 + fr0;
                bw[n] = *(const bf16x8*)(Bb + (size_t)row * 128 + ((lslot ^ sx) << 4));
            }
            __builtin_amdgcn_s_setprio(1);
            #pragma unroll
            for (int m = 0; m < 4; ++m)
                #pragma unroll
                for (int n = 0; n < 4; ++n)
                    acc[m][n] = __builtin_amdgcn_mfma_f32_16x16x32_bf16(
                        af[m], bw[n], acc[m][n], 0, 0, 0);
            __builtin_amdgcn_s_setprio(0);
        }
        __syncthreads();   // drains this iter's stage loads (vmcnt) + orders buffers
    }

    // ---- epilogue: plain store; label col uses exact fp32 phi;
    //      per-row (max, sumexp) partials, transposed layout [jcol][row] ----
    const int fr = lane & 15, q = lane >> 4;
    const int jcol = (nblk << 1) | wc;
    #pragma unroll
    for (int m = 0; m < 4; ++m) {
        #pragma unroll
        for (int j = 0; j < 4; ++j) {
            const int grow = m0 + wr * 64 + m * 16 + q * 4 + j;
            const int lab = label[grow];
            const float exv = exact_val[grow];
            float o[4]; int cc[4];
            float vmax = -1e30f;
            #pragma unroll
            for (int n = 0; n < 4; ++n) {
                const int col = c0 + wc * 64 + n * 16 + fr;   // < CPAD always
                float cosv = acc[m][n][j];
                if (BSRC == 1) cosv *= inv_norm[col];
                float val = (col == lab) ? exv : (S_F * cosv);
                o[n] = val; cc[n] = col;
                if (col < NCLS) {
                    out[(size_t)grow * NCLS + col] = val;
                    vmax = fmaxf(vmax, val);
                }
            }
            #pragma unroll
            for (int msk = 1; msk < 16; msk <<= 1)
                vmax = fmaxf(vmax, __shfl_xor(vmax, msk));
            float vsum = 0.0f;
            #pragma unroll
            for (int n = 0; n < 4; ++n)
                if (cc[n] < NCLS) vsum += __expf(o[n] - vmax);
            #pragma unroll
            for (int msk = 1; msk < 16; msk <<= 1)
                vsum += __shfl_xor(vsum, msk);
            if (fr == 0) {
                pmax[(size_t)jcol * BATCH + grow] = vmax;
                psum[(size_t)jcol * BATCH + grow] = vsum;
            }
        }
    }
}

// ---------------- K4: per-row lse + nll (partials transposed [jcol][row]) --------
__global__ __launch_bounds__(256) void row_lse_kernel(
    const float* __restrict__ pmax, const float* __restrict__ psum,
    const float* __restrict__ out, const int* __restrict__ label,
    float* __restrict__ nll) {
    const int row = blockIdx.x;
    const int t = threadIdx.x;
    float m = -1e30f, s = 0.f;
    for (int j = t; j < NJ; j += 256) {
        float pm = pmax[(size_t)j * BATCH + row];
        float ps = psum[(size_t)j * BATCH + row];
        float nm = fmaxf(m, pm);
        s = s * __expf(m - nm) + ps * __expf(pm - nm);
        m = nm;
    }
    #pragma unroll
    for (int msk = 1; msk < 64; msk <<= 1) {
        float om = __shfl_xor(m, msk), os = __shfl_xor(s, msk);
        float nm = fmaxf(m, om);
        s = s * __expf(m - nm) + os * __expf(om - nm);
        m = nm;
    }
    __shared__ float sm[4], ss[4];
    const int lane = t & 63, wid = t >> 6;
    if (lane == 0) { sm[wid] = m; ss[wid] = s; }
    __syncthreads();
    if (t == 0) {
        float M = sm[0], SS = ss[0];
        #pragma unroll
        for (int w = 1; w < 4; ++w) {
            float nm = fmaxf(M, sm[w]);
            SS = SS * __expf(M - nm) + ss[w] * __expf(sm[w] - nm);
            M = nm;
        }
        float lse = M + logf(SS);
        float tgt = out[(size_t)row * NCLS + label[row]];
        nll[row] = lse - tgt;
    }
}

// ---------------- K5: mean loss ----------------
__global__ __launch_bounds__(512) void loss_kernel(
    const float* __restrict__ nll, float* __restrict__ out_loss) {
    const int t = threadIdx.x;   // 512 threads
    float v = nll[t];
    #pragma unroll
    for (int msk = 1; msk < 64; msk <<= 1) v += __shfl_xor(v, msk);
    __shared__ float sv[8];
    if ((t & 63) == 0) sv[t >> 6] = v;
    __syncthreads();
    if (t == 0) {
        float s = 0.f;
        #pragma unroll
        for (int w = 0; w < 8; ++w) s += sv[w];
        out_loss[0] = s / 512.0f;
    }
}

// ---------------- host ----------------
extern "C" void kernel_launch(void* const* d_in, const int* in_sizes, int n_in,
                              void* d_out, int out_size, void* d_ws, size_t ws_size,
                              hipStream_t stream) {
    const float* input  = (const float*)d_in[0];
    const int*   label  = (const int*)d_in[1];
    const float* weight = (const float*)d_in[2];
    float* out = (float*)d_out;
    char* ws = (char*)d_ws;
    ushort_t* Abf  = (ushort_t*)(ws + WS_ABF);
    float*    pmax = (float*)(ws + WS_PMAX);
    float*    psum = (float*)(ws + WS_PSUM);
    float*    nll  = (float*)(ws + WS_NLL);
    float*    exv  = (float*)(ws + WS_EXACT);
    float*    invn = (float*)(ws + WS_INV);
    ushort_t* Wbf  = (ushort_t*)(ws + WS_WBF);

    // pick smallest chunk count (>=2 preferred for L3-hot B) that fits in ws
    size_t avail = ws_size > WS_WBF ? ws_size - WS_WBF : 0;
    int nch = 0, per = 0;
    const int cand[4] = {2, 4, 8, 16};
    for (int ci = 0; ci < 4; ++ci) {
        int p = (NBN + cand[ci] - 1) / cand[ci];
        if ((size_t)p * 128 * EMB * 2 <= avail) { nch = cand[ci]; per = p; break; }
    }

    cvt_input_kernel<<<dim3(256), dim3(256), 0, stream>>>(input, Abf);
    exact_label_kernel<<<dim3(128), dim3(256), 0, stream>>>(input, weight, label, exv);

    if (nch) {
        for (int c = 0; c < nch; ++c) {
            const int nb0 = c * per;
            int pc = NBN - nb0; if (pc > per) pc = per;
            if (pc <= 0) break;
            norms_chunk_kernel<<<dim3(pc * 32), dim3(256), 0, stream>>>(
                weight, Wbf, nb0 * 128);
            gemm_kernel<0><<<dim3(4 * pc), dim3(256), 0, stream>>>(
                Abf, weight, Wbf, invn, label, exv, out, pmax, psum, nb0);
        }
    } else {
        norms_inv_kernel<<<dim3(CPAD / 4), dim3(256), 0, stream>>>(weight, invn);
        gemm_kernel<1><<<dim3(4 * NBN), dim3(256), 0, stream>>>(
            Abf, weight, Wbf, invn, label, exv, out, pmax, psum, 0);
    }
    row_lse_kernel<<<dim3(512), dim3(256), 0, stream>>>(pmax, psum, out, label, nll);
    loss_kernel<<<dim3(1), dim3(512), 0, stream>>>(nll, out + (out_size - 1));
}